// Round 3
// baseline (119.533 us; speedup 1.0000x reference)
//
#include <hip/hip_runtime.h>
#include <math.h>

#define N 8192
#define IN_F 256
#define HID 256
#define ALPHA 0.2f

typedef float f32x4 __attribute__((ext_vector_type(4)));

__device__ __forceinline__ float dot4(const float4 a, const float4 b) {
    return a.x * b.x + a.y * b.y + a.z * b.z + a.w * b.w;
}

// ---------------------------------------------------------------------------
// Fused kernel AB:
//   phase 1 (per block, redundant, L2-hot): wa1[k] = W[k,:].a1, wa2[k] = W[k,:].a2
//           -> LDS. Each of 4 waves handles 64 W-rows, coalesced float4 loads.
//   phase 2: f1[i] = src[i,:].wa1, f2[i] = src[i,:].wa2 ; block owns 32 rows.
// grid = N/32 = 256 blocks x 256 threads.
// ---------------------------------------------------------------------------
__global__ __launch_bounds__(256) void compute_f_fused(
    const float* __restrict__ src, const float* __restrict__ W,
    const float* __restrict__ a, float* __restrict__ f1, float* __restrict__ f2) {
    __shared__ float wa1[HID];
    __shared__ float wa2[HID];
    const int wave = threadIdx.x >> 6, lane = threadIdx.x & 63;
    const float4 a1 = ((const float4*)(a))[lane];
    const float4 a2 = ((const float4*)(a + HID))[lane];

    // phase 1: wa into LDS
#pragma unroll 4
    for (int r = wave * 64; r < wave * 64 + 64; ++r) {
        const float4 w = ((const float4*)(W + r * HID))[lane];
        float s1 = dot4(w, a1);
        float s2 = dot4(w, a2);
#pragma unroll
        for (int off = 32; off > 0; off >>= 1) {
            s1 += __shfl_xor(s1, off);
            s2 += __shfl_xor(s2, off);
        }
        if (lane == 0) { wa1[r] = s1; wa2[r] = s2; }
    }
    __syncthreads();

    // phase 2: per-row dots
    const float4 x1 = ((const float4*)wa1)[lane];
    const float4 x2 = ((const float4*)wa2)[lane];
    const int row0 = blockIdx.x * 32 + wave * 8;
#pragma unroll
    for (int r = row0; r < row0 + 8; ++r) {
        const float4 v = ((const float4*)(src + (size_t)r * IN_F))[lane];
        float s1 = dot4(v, x1);
        float s2 = dot4(v, x2);
#pragma unroll
        for (int off = 32; off > 0; off >>= 1) {
            s1 += __shfl_xor(s1, off);
            s2 += __shfl_xor(s2, off);
        }
        if (lane == 0) { f1[r] = s1; f2[r] = s2; }
    }
}

// ---------------------------------------------------------------------------
// Kernel C: one block (512 threads) per row.
//   e = leaky(f1[row] + f2[col]) + bias[row][col]; row-softmax; store.
// All 8 loads issued before any arithmetic (max memory-level parallelism).
// Single-barrier softmax via per-wave max/sum + one LDS combine.
// bias/out streams nontemporal (touch-once); f2 cached (reused by all blocks).
// ---------------------------------------------------------------------------
__global__ __launch_bounds__(512) void attn_softmax(
    const float* __restrict__ bias, const float* __restrict__ f1,
    const float* __restrict__ f2, float* __restrict__ out) {
    const int row = blockIdx.x;
    const int t   = threadIdx.x;          // 0..511
    const float f1i = f1[row];

    const f32x4* __restrict__ brow = (const f32x4*)(bias + (size_t)row * N);
    const f32x4* __restrict__ f2v  = (const f32x4*)f2;
    f32x4* __restrict__ orow       = (f32x4*)(out + (size_t)row * N);

    // batch-issue all loads
    f32x4 b[4], g[4];
#pragma unroll
    for (int u = 0; u < 4; ++u) b[u] = __builtin_nontemporal_load(&brow[u * 512 + t]);
#pragma unroll
    for (int u = 0; u < 4; ++u) g[u] = f2v[u * 512 + t];

    float e[16];
    float lmax = -3.4e38f;
#pragma unroll
    for (int u = 0; u < 4; ++u) {
        f32x4 v = f1i + g[u];
        // leaky(v) = max(v, alpha*v) for 0<alpha<1
        v.x = fmaxf(v.x, ALPHA * v.x) + b[u].x;
        v.y = fmaxf(v.y, ALPHA * v.y) + b[u].y;
        v.z = fmaxf(v.z, ALPHA * v.z) + b[u].z;
        v.w = fmaxf(v.w, ALPHA * v.w) + b[u].w;
        e[u * 4 + 0] = v.x; e[u * 4 + 1] = v.y;
        e[u * 4 + 2] = v.z; e[u * 4 + 3] = v.w;
        lmax = fmaxf(lmax, fmaxf(fmaxf(v.x, v.y), fmaxf(v.z, v.w)));
    }

    // per-wave max
#pragma unroll
    for (int off = 32; off > 0; off >>= 1) lmax = fmaxf(lmax, __shfl_xor(lmax, off));

    // exp relative to wave max + per-wave sum
    float lsum = 0.f;
#pragma unroll
    for (int i = 0; i < 16; ++i) {
        e[i] = __expf(e[i] - lmax);
        lsum += e[i];
    }
#pragma unroll
    for (int off = 32; off > 0; off >>= 1) lsum += __shfl_xor(lsum, off);

    __shared__ float wm[8];
    __shared__ float wsum[8];
    const int wave = t >> 6, lane = t & 63;
    if (lane == 0) { wm[wave] = lmax; wsum[wave] = lsum; }
    __syncthreads();                       // the ONLY barrier

    float M = wm[0];
#pragma unroll
    for (int w = 1; w < 8; ++w) M = fmaxf(M, wm[w]);
    float S = 0.f;
#pragma unroll
    for (int w = 0; w < 8; ++w) S += wsum[w] * __expf(wm[w] - M);
    const float scale = __expf(lmax - M) / S;   // fold wave-max correction into denom

#pragma unroll
    for (int u = 0; u < 4; ++u) {
        f32x4 v;
        v.x = e[u * 4 + 0] * scale; v.y = e[u * 4 + 1] * scale;
        v.z = e[u * 4 + 2] * scale; v.w = e[u * 4 + 3] * scale;
        __builtin_nontemporal_store(v, &orow[u * 512 + t]);
    }
}

extern "C" void kernel_launch(void* const* d_in, const int* in_sizes, int n_in,
                              void* d_out, int out_size, void* d_ws, size_t ws_size,
                              hipStream_t stream) {
    const float* src  = (const float*)d_in[0];   // (8192, 256)
    const float* bias = (const float*)d_in[1];   // (8192, 8192)
    const float* W    = (const float*)d_in[2];   // (256, 256)
    const float* a    = (const float*)d_in[3];   // (512, 1)
    float* out = (float*)d_out;

    // workspace layout (floats): f1[0:8192), f2[8192:16384)
    float* ws = (float*)d_ws;
    float* f1 = ws;
    float* f2 = ws + N;

    compute_f_fused<<<N / 32, 256, 0, stream>>>(src, W, a, f1, f2);
    attn_softmax<<<N, 512, 0, stream>>>(bias, f1, f2, out);
}

// Round 4
// 100.200 us; speedup vs baseline: 1.1929x; 1.1929x over previous
//
#include <hip/hip_runtime.h>
#include <math.h>

#define N 8192
#define IN_F 256
#define HID 256
#define ALPHA 0.2f

typedef float f32x4 __attribute__((ext_vector_type(4)));

// ---------------------------------------------------------------------------
// Kernel A: wa1[m] = sum_k W[m][k]*a1[k], wa2[m] = sum_k W[m][k]*a2[k]
// 256 blocks (one per m), 64 threads, coalesced float4 row read, one
// shuffle-reduce per block -> fully parallel (the round-3 fusion serialized
// this into 64 dependent reduces per wave and cost +20us; keep it parallel).
// ---------------------------------------------------------------------------
__global__ void compute_wa(const float* __restrict__ W, const float* __restrict__ a,
                           float* __restrict__ wa /* [512]: wa1 | wa2 */) {
    const int m = blockIdx.x;
    const int lane = threadIdx.x;                 // 0..63
    const float4 w  = ((const float4*)(W + m * HID))[lane];
    const float4 a1 = ((const float4*)(a))[lane];
    const float4 a2 = ((const float4*)(a + HID))[lane];
    float s1 = w.x * a1.x + w.y * a1.y + w.z * a1.z + w.w * a1.w;
    float s2 = w.x * a2.x + w.y * a2.y + w.z * a2.z + w.w * a2.w;
#pragma unroll
    for (int off = 32; off > 0; off >>= 1) {
        s1 += __shfl_xor(s1, off);
        s2 += __shfl_xor(s2, off);
    }
    if (lane == 0) {
        wa[m]       = s1;
        wa[HID + m] = s2;
    }
}

// ---------------------------------------------------------------------------
// Kernel B: f1[i] = src[i,:] . wa1, f2[i] = src[i,:] . wa2
// One wave per row; 4 rows per 256-thread block; 2048 blocks (parallel).
// ---------------------------------------------------------------------------
__global__ void compute_f(const float* __restrict__ src, const float* __restrict__ wa,
                          float* __restrict__ f1, float* __restrict__ f2) {
    const int wave = threadIdx.x >> 6;
    const int lane = threadIdx.x & 63;
    const int row  = blockIdx.x * 4 + wave;
    const float4 v  = ((const float4*)(src + (size_t)row * IN_F))[lane];
    const float4 x1 = ((const float4*)(wa))[lane];
    const float4 x2 = ((const float4*)(wa + HID))[lane];
    float s1 = v.x * x1.x + v.y * x1.y + v.z * x1.z + v.w * x1.w;
    float s2 = v.x * x2.x + v.y * x2.y + v.z * x2.z + v.w * x2.w;
#pragma unroll
    for (int off = 32; off > 0; off >>= 1) {
        s1 += __shfl_xor(s1, off);
        s2 += __shfl_xor(s2, off);
    }
    if (lane == 0) {
        f1[row] = s1;
        f2[row] = s2;
    }
}

// ---------------------------------------------------------------------------
// Kernel C: one block (512 threads) per row.
//   e = leaky(f1[row] + f2[col]) + bias[row][col]; row-softmax; store.
// Single-barrier softmax: per-wave max m_w, per-wave sum s_w = sum exp(e-m_w);
// after ONE __syncthreads: M = max m_w, S = sum s_w*exp(m_w-M),
// out = exp(e-m_w) * exp(m_w-M)/S == exp(e-M)/S exactly.
// bias/out nontemporal (touch-once, keep out of L2); f2 cached (reused).
// ---------------------------------------------------------------------------
__global__ __launch_bounds__(512) void attn_softmax(
    const float* __restrict__ bias, const float* __restrict__ f1,
    const float* __restrict__ f2, float* __restrict__ out) {
    const int row = blockIdx.x;
    const int t   = threadIdx.x;          // 0..511
    const float f1i = f1[row];

    const f32x4* __restrict__ brow = (const f32x4*)(bias + (size_t)row * N);
    const f32x4* __restrict__ f2v  = (const f32x4*)f2;
    f32x4* __restrict__ orow       = (f32x4*)(out + (size_t)row * N);

    float e[16];
    float lmax = -3.4e38f;
#pragma unroll
    for (int u = 0; u < 4; ++u) {
        const int idx = u * 512 + t;
        const f32x4 b = __builtin_nontemporal_load(&brow[idx]);
        const f32x4 g = f2v[idx];
        f32x4 v = f1i + g;
        // leaky(x) = max(x, alpha*x) for 0<alpha<1
        v.x = fmaxf(v.x, ALPHA * v.x) + b.x;
        v.y = fmaxf(v.y, ALPHA * v.y) + b.y;
        v.z = fmaxf(v.z, ALPHA * v.z) + b.z;
        v.w = fmaxf(v.w, ALPHA * v.w) + b.w;
        e[u * 4 + 0] = v.x; e[u * 4 + 1] = v.y;
        e[u * 4 + 2] = v.z; e[u * 4 + 3] = v.w;
        lmax = fmaxf(lmax, fmaxf(fmaxf(v.x, v.y), fmaxf(v.z, v.w)));
    }

    // per-wave max
#pragma unroll
    for (int off = 32; off > 0; off >>= 1) lmax = fmaxf(lmax, __shfl_xor(lmax, off));

    // exp relative to wave max + per-wave sum
    float lsum = 0.f;
#pragma unroll
    for (int i = 0; i < 16; ++i) {
        e[i] = __expf(e[i] - lmax);
        lsum += e[i];
    }
#pragma unroll
    for (int off = 32; off > 0; off >>= 1) lsum += __shfl_xor(lsum, off);

    __shared__ float wm[8];
    __shared__ float wsum[8];
    const int wave = t >> 6, lane = t & 63;
    if (lane == 0) { wm[wave] = lmax; wsum[wave] = lsum; }
    __syncthreads();                       // the ONLY barrier

    float M = wm[0];
#pragma unroll
    for (int w = 1; w < 8; ++w) M = fmaxf(M, wm[w]);
    float S = 0.f;
#pragma unroll
    for (int w = 0; w < 8; ++w) S += wsum[w] * __expf(wm[w] - M);
    const float scale = __expf(lmax - M) / S;   // per-wave correction / denom

#pragma unroll
    for (int u = 0; u < 4; ++u) {
        const int idx = u * 512 + t;
        f32x4 v;
        v.x = e[u * 4 + 0] * scale; v.y = e[u * 4 + 1] * scale;
        v.z = e[u * 4 + 2] * scale; v.w = e[u * 4 + 3] * scale;
        __builtin_nontemporal_store(v, &orow[idx]);
    }
}

extern "C" void kernel_launch(void* const* d_in, const int* in_sizes, int n_in,
                              void* d_out, int out_size, void* d_ws, size_t ws_size,
                              hipStream_t stream) {
    const float* src  = (const float*)d_in[0];   // (8192, 256)
    const float* bias = (const float*)d_in[1];   // (8192, 8192)
    const float* W    = (const float*)d_in[2];   // (256, 256)
    const float* a    = (const float*)d_in[3];   // (512, 1)
    float* out = (float*)d_out;

    // workspace layout (floats): wa[0:512), f1[512:8704), f2[8704:16896)
    float* ws = (float*)d_ws;
    float* wa = ws;
    float* f1 = ws + 512;
    float* f2 = ws + 512 + N;

    compute_wa<<<HID, 64, 0, stream>>>(W, a, wa);
    compute_f<<<N / 4, 256, 0, stream>>>(src, wa, f1, f2);
    attn_softmax<<<N, 512, 0, stream>>>(bias, f1, f2, out);
}